// Round 4
// baseline (17965.346 us; speedup 1.0000x reference)
//
#include <hip/hip_runtime.h>

#define T_SEQ 16384
#define HID   128
#define G4    512
#define NW    6              // worker blocks
#define NCHUNK (T_SEQ / 64)  // 256
#define RSTEPS 2048          // pre2 ring (steps)
#define RMASK  (RSTEPS - 1)

typedef _Float16 half2t __attribute__((ext_vector_type(2)));

__device__ __forceinline__ float sigm(float x) {
    float e = __expf(-x);
    return __builtin_amdgcn_rcpf(1.0f + e);
}
__device__ __forceinline__ float tanh_(float x) {
    float e = __expf(-2.0f * x);
    return __builtin_amdgcn_rcpf(1.0f + e) * 2.0f - 1.0f;
}
__device__ __forceinline__ half2t pack2(float lo, float hi) {
    half2t v; v.x = (_Float16)lo; v.y = (_Float16)hi; return v;
}
__device__ __forceinline__ half2t bc(float x) { return __builtin_bit_cast(half2t, x); }
// quad_perm butterfly add: 0xB1 = xor1, 0x4E = xor2
template <int CTRL>
__device__ __forceinline__ float dppadd(float p) {
    int v = __builtin_bit_cast(int, p);
    int t = __builtin_amdgcn_update_dpp(v, v, CTRL, 0xf, 0xf, false);
    return p + __builtin_bit_cast(float, t);
}
// barrier draining LDS ops only; global ops stay in flight
__device__ __forceinline__ void bar() {
    asm volatile("s_waitcnt lgkmcnt(0)" ::: "memory");
    __builtin_amdgcn_s_barrier();
    asm volatile("" ::: "memory");
}
#define AGENT __HIP_MEMORY_SCOPE_AGENT

// ---------------------------------------------------------------------------
// Kernel 1: pre1h[t][r] = f16( (b_ih1[r]+b_hh1[r]) + x[t]·W_ih1[r] )
// ---------------------------------------------------------------------------
__global__ __launch_bounds__(512, 1)
void pre1_gemm(const float* __restrict__ x, const float* __restrict__ Wih1,
               const float* __restrict__ bih1, const float* __restrict__ bhh1,
               _Float16* __restrict__ pre1h)
{
    __shared__ float xs[16][50];
    const int r  = threadIdx.x;
    const int t0 = blockIdx.x * 16;
    for (int i = r; i < 16 * 50; i += 512) xs[i / 50][i % 50] = x[t0 * 50 + i];
    __syncthreads();
    float wr[50];
#pragma unroll
    for (int k = 0; k < 50; ++k) wr[k] = Wih1[r * 50 + k];
    const float bias = bih1[r] + bhh1[r];
    for (int tt = 0; tt < 16; ++tt) {
        float acc = bias;
#pragma unroll
        for (int k = 0; k < 50; ++k) acc = fmaf(wr[k], xs[tt][k], acc);
        pre1h[(size_t)(t0 + tt) * G4 + r] = (_Float16)acc;
    }
}

// ---------------------------------------------------------------------------
// Kernel 2: 3-stage pipeline, one kernel, 2+NW blocks of 1024 threads.
//  Block 0 (A): L1 recurrence. Thread = (rg=4-row group, ks=16-wide k-slice);
//    32 weight VGPRs; DPP quad-reduce -> G0/G1 half-sums; gate waves finish.
//    Exports h1 (f16-packed u32) + progress flag per 64 steps.
//  Blocks 2.. (W): parallel GEMM pre2 = b2 + Wih2 @ h1chunk -> ring + done[c].
//  Block 1 (C): L2 recurrence, same structure as A, consumes pre2 ring.
// ---------------------------------------------------------------------------
__global__ __launch_bounds__(1024, 4)
void lstm3(const _Float16* __restrict__ pre1h,
           const float* __restrict__ Whh1, const float* __restrict__ Wih2,
           const float* __restrict__ Whh2, const float* __restrict__ bih2,
           const float* __restrict__ bhh2,
           unsigned* __restrict__ h1g,     // [T][64] u32 (2xf16)
           unsigned* __restrict__ pre2r,   // ring [RSTEPS][512] f32-bits
           unsigned* __restrict__ fl,      // flags: prog=fl[0], cons=fl[32], done=fl[64..]
           float* __restrict__ h2out)
{
    __shared__ __align__(16) _Float16 HS[2][HID];
    __shared__ __align__(16) float G0[4 * 132], G1[4 * 132];
    __shared__ __align__(16) _Float16 H1c[64][HID];   // worker: h1 chunk
    __shared__ __align__(16) float PW[16][1024];      // worker: half-partials

    const int tid  = threadIdx.x;
    const int lane = tid & 63, wv = tid >> 6;
    const int ks   = lane & 7;
    const int rg   = (wv << 3) | (lane >> 3);         // [0,128)
    const int gate = rg >> 5, ub = (rg & 31) << 2;
    const int gbase = gate * 132 + ub;
    unsigned* prog = fl;
    unsigned* cons = fl + 32;
    unsigned* done = fl + 64;

    if (blockIdx.x == 0) {
        // ===================== stage A: layer-1 recurrence =====================
        half2t w[4][8];
#pragma unroll
        for (int i = 0; i < 4; ++i) {
            const float4* wp = (const float4*)(Whh1 + (size_t)(4 * rg + i) * HID + ks * 16);
            float4 q0 = wp[0], q1 = wp[1], q2 = wp[2], q3 = wp[3];
            w[i][0] = pack2(q0.x, q0.y); w[i][1] = pack2(q0.z, q0.w);
            w[i][2] = pack2(q1.x, q1.y); w[i][3] = pack2(q1.z, q1.w);
            w[i][4] = pack2(q2.x, q2.y); w[i][5] = pack2(q2.z, q2.w);
            w[i][6] = pack2(q3.x, q3.y); w[i][7] = pack2(q3.z, q3.w);
        }
        for (int k = tid; k < 2 * HID; k += 1024) ((_Float16*)HS)[k] = (_Float16)0.f;
        float4 pcur = make_float4(0.f, 0.f, 0.f, 0.f);
        if (ks == 0) {
            uint2 p0 = *(const uint2*)(pre1h + 4 * rg);
            half2t a = __builtin_bit_cast(half2t, p0.x), b = __builtin_bit_cast(half2t, p0.y);
            pcur = make_float4((float)a.x, (float)a.y, (float)b.x, (float)b.y);
        }
        float c1 = 0.f;
        __syncthreads();

        for (int s = 0; s < T_SEQ; ++s) {
            const int rs = s & 1;
            uint2 pnext = make_uint2(0u, 0u);
            if (ks == 0 && s + 1 < T_SEQ)
                pnext = *(const uint2*)(pre1h + (size_t)(s + 1) * G4 + 4 * rg);
            // ---- dot phase ----
            const float4* hp = (const float4*)&HS[rs][ks * 16];
            float4 v0 = hp[0], v1 = hp[1];
            half2t hv0 = bc(v0.x), hv1 = bc(v0.y), hv2 = bc(v0.z), hv3 = bc(v0.w);
            half2t hv4 = bc(v1.x), hv5 = bc(v1.y), hv6 = bc(v1.z), hv7 = bc(v1.w);
            float p0 = 0.f, p1 = 0.f, p2 = 0.f, p3 = 0.f;
#define DOT4(H) p0 = __builtin_amdgcn_fdot2(w[0][__k], H, p0, false); \
                p1 = __builtin_amdgcn_fdot2(w[1][__k], H, p1, false); \
                p2 = __builtin_amdgcn_fdot2(w[2][__k], H, p2, false); \
                p3 = __builtin_amdgcn_fdot2(w[3][__k], H, p3, false);
            { enum { __k = 0 }; DOT4(hv0) } { enum { __k = 1 }; DOT4(hv1) }
            { enum { __k = 2 }; DOT4(hv2) } { enum { __k = 3 }; DOT4(hv3) }
            { enum { __k = 4 }; DOT4(hv4) } { enum { __k = 5 }; DOT4(hv5) }
            { enum { __k = 6 }; DOT4(hv6) } { enum { __k = 7 }; DOT4(hv7) }
            p0 = dppadd<0xB1>(p0); p0 = dppadd<0x4E>(p0);
            p1 = dppadd<0xB1>(p1); p1 = dppadd<0x4E>(p1);
            p2 = dppadd<0xB1>(p2); p2 = dppadd<0x4E>(p2);
            p3 = dppadd<0xB1>(p3); p3 = dppadd<0x4E>(p3);
            if (ks == 0)
                *(float4*)&G0[gbase] = make_float4(p0 + pcur.x, p1 + pcur.y, p2 + pcur.z, p3 + pcur.w);
            if (ks == 4)
                *(float4*)&G1[gbase] = make_float4(p0, p1, p2, p3);
            bar();
            // ---- gate phase ----
            if (tid < HID) {
                const int u = tid;
                float gi = G0[u] + G1[u];
                float gf = G0[132 + u] + G1[132 + u];
                float gg = G0[264 + u] + G1[264 + u];
                float go = G0[396 + u] + G1[396 + u];
                float i_ = sigm(gi), f_ = sigm(gf), g_ = tanh_(gg), o_ = sigm(go);
                c1 = f_ * c1 + i_ * g_;
                float h = o_ * tanh_(c1);
                HS[rs ^ 1][u] = (_Float16)h;
                unsigned hb = (unsigned)__builtin_bit_cast(unsigned short, (_Float16)h);
                unsigned pb = __shfl_xor(hb, 1);
                if ((u & 1) == 0)
                    __hip_atomic_store(h1g + (size_t)s * 64 + (u >> 1), hb | (pb << 16),
                                       __ATOMIC_RELAXED, AGENT);
            }
            if ((s & 63) == 63) {
                if (tid < HID) asm volatile("s_waitcnt vmcnt(0)" ::: "memory");
                bar();
                if (tid == 0)
                    __hip_atomic_store(prog, (unsigned)((s >> 6) + 1), __ATOMIC_RELEASE, AGENT);
            } else bar();
            if (ks == 0) {
                half2t a = __builtin_bit_cast(half2t, pnext.x), b = __builtin_bit_cast(half2t, pnext.y);
                pcur = make_float4((float)a.x, (float)a.y, (float)b.x, (float)b.y);
            }
        }
    } else if (blockIdx.x == 1) {
        // ===================== stage C: layer-2 recurrence =====================
        half2t w[4][8];
#pragma unroll
        for (int i = 0; i < 4; ++i) {
            const float4* wp = (const float4*)(Whh2 + (size_t)(4 * rg + i) * HID + ks * 16);
            float4 q0 = wp[0], q1 = wp[1], q2 = wp[2], q3 = wp[3];
            w[i][0] = pack2(q0.x, q0.y); w[i][1] = pack2(q0.z, q0.w);
            w[i][2] = pack2(q1.x, q1.y); w[i][3] = pack2(q1.z, q1.w);
            w[i][4] = pack2(q2.x, q2.y); w[i][5] = pack2(q2.z, q2.w);
            w[i][6] = pack2(q3.x, q3.y); w[i][7] = pack2(q3.z, q3.w);
        }
        for (int k = tid; k < 2 * HID; k += 1024) ((_Float16*)HS)[k] = (_Float16)0.f;
        float c2 = 0.f;
        if (tid == 0)
            while (!__hip_atomic_load(done + 0, __ATOMIC_ACQUIRE, AGENT))
                __builtin_amdgcn_s_sleep(8);
        __syncthreads();
        float4 pcur = make_float4(0.f, 0.f, 0.f, 0.f);
        unsigned n0 = 0, n1 = 0, n2 = 0, n3 = 0;
        if (ks == 0) {
            size_t b = (size_t)0 * G4 + 4 * rg;
            pcur.x = __uint_as_float(__hip_atomic_load(pre2r + b + 0, __ATOMIC_RELAXED, AGENT));
            pcur.y = __uint_as_float(__hip_atomic_load(pre2r + b + 1, __ATOMIC_RELAXED, AGENT));
            pcur.z = __uint_as_float(__hip_atomic_load(pre2r + b + 2, __ATOMIC_RELAXED, AGENT));
            pcur.w = __uint_as_float(__hip_atomic_load(pre2r + b + 3, __ATOMIC_RELAXED, AGENT));
        }
        for (int s = 0; s < T_SEQ; ++s) {
            const int rs = s & 1;
            const bool boundary = ((s + 1) & 63) == 0;
            if (ks == 0 && !boundary && s + 1 < T_SEQ) {
                size_t b = (size_t)((s + 1) & RMASK) * G4 + 4 * rg;
                n0 = __hip_atomic_load(pre2r + b + 0, __ATOMIC_RELAXED, AGENT);
                n1 = __hip_atomic_load(pre2r + b + 1, __ATOMIC_RELAXED, AGENT);
                n2 = __hip_atomic_load(pre2r + b + 2, __ATOMIC_RELAXED, AGENT);
                n3 = __hip_atomic_load(pre2r + b + 3, __ATOMIC_RELAXED, AGENT);
            }
            const float4* hp = (const float4*)&HS[rs][ks * 16];
            float4 v0 = hp[0], v1 = hp[1];
            half2t hv0 = bc(v0.x), hv1 = bc(v0.y), hv2 = bc(v0.z), hv3 = bc(v0.w);
            half2t hv4 = bc(v1.x), hv5 = bc(v1.y), hv6 = bc(v1.z), hv7 = bc(v1.w);
            float p0 = 0.f, p1 = 0.f, p2 = 0.f, p3 = 0.f;
            { enum { __k = 0 }; DOT4(hv0) } { enum { __k = 1 }; DOT4(hv1) }
            { enum { __k = 2 }; DOT4(hv2) } { enum { __k = 3 }; DOT4(hv3) }
            { enum { __k = 4 }; DOT4(hv4) } { enum { __k = 5 }; DOT4(hv5) }
            { enum { __k = 6 }; DOT4(hv6) } { enum { __k = 7 }; DOT4(hv7) }
            p0 = dppadd<0xB1>(p0); p0 = dppadd<0x4E>(p0);
            p1 = dppadd<0xB1>(p1); p1 = dppadd<0x4E>(p1);
            p2 = dppadd<0xB1>(p2); p2 = dppadd<0x4E>(p2);
            p3 = dppadd<0xB1>(p3); p3 = dppadd<0x4E>(p3);
            if (ks == 0)
                *(float4*)&G0[gbase] = make_float4(p0 + pcur.x, p1 + pcur.y, p2 + pcur.z, p3 + pcur.w);
            if (ks == 4)
                *(float4*)&G1[gbase] = make_float4(p0, p1, p2, p3);
            bar();
            if (tid < HID) {
                const int u = tid;
                float gi = G0[u] + G1[u];
                float gf = G0[132 + u] + G1[132 + u];
                float gg = G0[264 + u] + G1[264 + u];
                float go = G0[396 + u] + G1[396 + u];
                float i_ = sigm(gi), f_ = sigm(gf), g_ = tanh_(gg), o_ = sigm(go);
                c2 = f_ * c2 + i_ * g_;
                float h = o_ * tanh_(c2);
                HS[rs ^ 1][u] = (_Float16)h;
                h2out[(size_t)s * HID + u] = h;
            }
            if ((s & 63) == 63) {
                bar();
                if (tid == 0)
                    __hip_atomic_store(cons, (unsigned)((s >> 6) + 1), __ATOMIC_RELAXED, AGENT);
            } else bar();
            if (boundary && s + 1 < T_SEQ) {
                if (tid == 0)
                    while (!__hip_atomic_load(done + ((s + 1) >> 6), __ATOMIC_ACQUIRE, AGENT))
                        __builtin_amdgcn_s_sleep(8);
                bar();
                if (ks == 0) {
                    size_t b = (size_t)((s + 1) & RMASK) * G4 + 4 * rg;
                    pcur.x = __uint_as_float(__hip_atomic_load(pre2r + b + 0, __ATOMIC_RELAXED, AGENT));
                    pcur.y = __uint_as_float(__hip_atomic_load(pre2r + b + 1, __ATOMIC_RELAXED, AGENT));
                    pcur.z = __uint_as_float(__hip_atomic_load(pre2r + b + 2, __ATOMIC_RELAXED, AGENT));
                    pcur.w = __uint_as_float(__hip_atomic_load(pre2r + b + 3, __ATOMIC_RELAXED, AGENT));
                }
            } else if (ks == 0) {
                pcur = make_float4(__uint_as_float(n0), __uint_as_float(n1),
                                   __uint_as_float(n2), __uint_as_float(n3));
            }
        }
    } else {
        // ===================== workers: pre2 chunk GEMM =====================
        const int wk  = blockIdx.x - 2;
        const int row = tid & 511, half = tid >> 9;
        half2t wr[32];
        {
            const float4* wp = (const float4*)(Wih2 + (size_t)row * HID + half * 64);
#pragma unroll
            for (int m = 0; m < 8; ++m) {
                float4 a = wp[2 * m], b = wp[2 * m + 1];
                wr[4 * m + 0] = pack2(a.x, a.y); wr[4 * m + 1] = pack2(a.z, a.w);
                wr[4 * m + 2] = pack2(b.x, b.y); wr[4 * m + 3] = pack2(b.z, b.w);
            }
        }
        const float brow = (half == 0) ? (bih2[row] + bhh2[row]) : 0.f;
        for (int c = wk; c < NCHUNK; c += NW) {
            if (tid == 0) {
                while (__hip_atomic_load(prog, __ATOMIC_ACQUIRE, AGENT) < (unsigned)(c + 1))
                    __builtin_amdgcn_s_sleep(8);
                while ((int)__hip_atomic_load(cons, __ATOMIC_RELAXED, AGENT) < c - 24)
                    __builtin_amdgcn_s_sleep(8);
            }
            __syncthreads();
            {   // stage h1 chunk into LDS
                unsigned* dst = (unsigned*)&H1c[0][0];
                const size_t gb = (size_t)c * 4096;
#pragma unroll
                for (int q = 0; q < 4; ++q)
                    dst[tid + 1024 * q] =
                        __hip_atomic_load(h1g + gb + tid + 1024 * q, __ATOMIC_RELAXED, AGENT);
            }
            __syncthreads();
            for (int tile = 0; tile < 4; ++tile) {
                float p[16];
#pragma unroll
                for (int j = 0; j < 16; ++j) {
                    const float4* hp = (const float4*)&H1c[tile * 16 + j][half * 64];
                    float a = brow;
#pragma unroll
                    for (int m = 0; m < 8; ++m) {
                        float4 vv = hp[m];
                        a = __builtin_amdgcn_fdot2(wr[4 * m + 0], bc(vv.x), a, false);
                        a = __builtin_amdgcn_fdot2(wr[4 * m + 1], bc(vv.y), a, false);
                        a = __builtin_amdgcn_fdot2(wr[4 * m + 2], bc(vv.z), a, false);
                        a = __builtin_amdgcn_fdot2(wr[4 * m + 3], bc(vv.w), a, false);
                    }
                    p[j] = a;
                }
#pragma unroll
                for (int j = 0; j < 16; ++j) PW[j][half * 512 + row] = p[j];
                __syncthreads();
                {
                    const int j2 = wv, r8 = lane * 8;
                    float4 a0 = *(const float4*)&PW[j2][r8];
                    float4 a1 = *(const float4*)&PW[j2][r8 + 4];
                    float4 b0 = *(const float4*)&PW[j2][512 + r8];
                    float4 b1 = *(const float4*)&PW[j2][512 + r8 + 4];
                    const size_t base = (size_t)((c * 64 + tile * 16 + j2) & RMASK) * G4 + r8;
                    __hip_atomic_store(pre2r + base + 0, __float_as_uint(a0.x + b0.x), __ATOMIC_RELAXED, AGENT);
                    __hip_atomic_store(pre2r + base + 1, __float_as_uint(a0.y + b0.y), __ATOMIC_RELAXED, AGENT);
                    __hip_atomic_store(pre2r + base + 2, __float_as_uint(a0.z + b0.z), __ATOMIC_RELAXED, AGENT);
                    __hip_atomic_store(pre2r + base + 3, __float_as_uint(a0.w + b0.w), __ATOMIC_RELAXED, AGENT);
                    __hip_atomic_store(pre2r + base + 4, __float_as_uint(a1.x + b1.x), __ATOMIC_RELAXED, AGENT);
                    __hip_atomic_store(pre2r + base + 5, __float_as_uint(a1.y + b1.y), __ATOMIC_RELAXED, AGENT);
                    __hip_atomic_store(pre2r + base + 6, __float_as_uint(a1.z + b1.z), __ATOMIC_RELAXED, AGENT);
                    __hip_atomic_store(pre2r + base + 7, __float_as_uint(a1.w + b1.w), __ATOMIC_RELAXED, AGENT);
                }
                __syncthreads();
            }
            asm volatile("s_waitcnt vmcnt(0)" ::: "memory");
            __syncthreads();
            if (tid == 0)
                __hip_atomic_store(done + c, 1u, __ATOMIC_RELEASE, AGENT);
        }
    }
#undef DOT4
}

// ---------------------------------------------------------------------------
// Kernel 3: out[t][o] = fc_b[o] + h2[t]·fc_W[o]
// ---------------------------------------------------------------------------
__global__ __launch_bounds__(256, 1)
void fc_kernel(const float* __restrict__ h2, const float* __restrict__ fcW,
               const float* __restrict__ fcb, float* __restrict__ out)
{
    __shared__ float wls[5 * HID];
    __shared__ float bls[5];
    for (int i = threadIdx.x; i < 5 * HID; i += 256) wls[i] = fcW[i];
    if (threadIdx.x < 5) bls[threadIdx.x] = fcb[threadIdx.x];
    __syncthreads();
    const int t = blockIdx.x * blockDim.x + threadIdx.x;
    if (t >= T_SEQ) return;
    const float* hrow = h2 + (size_t)t * HID;
    float a0 = bls[0], a1 = bls[1], a2 = bls[2], a3 = bls[3], a4 = bls[4];
#pragma unroll
    for (int k = 0; k < HID; ++k) {
        float hv = hrow[k];
        a0 = fmaf(hv, wls[k], a0);
        a1 = fmaf(hv, wls[HID + k], a1);
        a2 = fmaf(hv, wls[2 * HID + k], a2);
        a3 = fmaf(hv, wls[3 * HID + k], a3);
        a4 = fmaf(hv, wls[4 * HID + k], a4);
    }
    float* orow = out + (size_t)t * 5;
    orow[0] = a0; orow[1] = a1; orow[2] = a2; orow[3] = a3; orow[4] = a4;
}

// ---------------------------------------------------------------------------
extern "C" void kernel_launch(void* const* d_in, const int* in_sizes, int n_in,
                              void* d_out, int out_size, void* d_ws, size_t ws_size,
                              hipStream_t stream) {
    const float* x    = (const float*)d_in[0];
    const float* Wih1 = (const float*)d_in[1];
    const float* Whh1 = (const float*)d_in[2];
    const float* bih1 = (const float*)d_in[3];
    const float* bhh1 = (const float*)d_in[4];
    const float* Wih2 = (const float*)d_in[5];
    const float* Whh2 = (const float*)d_in[6];
    const float* bih2 = (const float*)d_in[7];
    const float* bhh2 = (const float*)d_in[8];
    const float* fcW  = (const float*)d_in[9];
    const float* fcb  = (const float*)d_in[10];
    float* out = (float*)d_out;

    // ws: pre1h 16MB | h1g 4MB | pre2r 4MB | h2buf 8MB | flags 2KB  (= 32MB+2KB)
    char* w = (char*)d_ws;
    _Float16* pre1h = (_Float16*)(w);
    unsigned* h1g   = (unsigned*)(w + (16u << 20));
    unsigned* pre2r = (unsigned*)(w + (20u << 20));
    float*    h2buf = (float*)(w + (24u << 20));
    unsigned* fl    = (unsigned*)(w + (32u << 20));

    hipMemsetAsync(fl, 0, 2048, stream);
    pre1_gemm<<<T_SEQ / 16, 512, 0, stream>>>(x, Wih1, bih1, bhh1, pre1h);
    lstm3<<<2 + NW, 1024, 0, stream>>>(pre1h, Whh1, Wih2, Whh2, bih2, bhh2,
                                       h1g, pre2r, fl, h2buf);
    fc_kernel<<<(T_SEQ + 255) / 256, 256, 0, stream>>>(h2buf, fcW, fcb, out);
}